// Round 1
// baseline (703.232 us; speedup 1.0000x reference)
//
#include <hip/hip_runtime.h>
#include <hip/hip_bf16.h>

typedef _Float16 half8 __attribute__((ext_vector_type(8)));
typedef float floatx4 __attribute__((ext_vector_type(4)));

#define SEQ 2048
#define DIM 2048
#define HQ 32
#define HKV 8
#define HD 64
#define NQ (HQ*HD)    /* 2048 */
#define NK (HKV*HD)   /* 512  */
#define NTOT (NQ+NK)  /* 2560 */

// ---------------------------------------------------------------------------
// Kernel 0: fp32 -> fp16 conversion of X and concatenated [Wq; Wk]
// ---------------------------------------------------------------------------
__global__ void convert_kernel(const float* __restrict__ X,
                               const float* __restrict__ Wq,
                               const float* __restrict__ Wk,
                               _Float16* __restrict__ Xh,
                               _Float16* __restrict__ Wh) {
    long i = (long)blockIdx.x * 256 + threadIdx.x;
    const long nx = (long)SEQ * DIM;      // 4194304
    const long nw = (long)NTOT * DIM;     // 5242880
    if (i < nx) {
        Xh[i] = (_Float16)X[i];
    } else if (i < nx + nw) {
        long j = i - nx;
        float v = (j < (long)NQ * DIM) ? Wq[j] : Wk[j - (long)NQ * DIM];
        Wh[j] = (_Float16)v;
    }
}

// ---------------------------------------------------------------------------
// Kernel 1: fused QK projection GEMM (fp16 MFMA) + RoPE epilogue
// C[s][n] = sum_k X[s][k] * W[n][k]   (NT gemm, both operands row-major [row][k])
// Tile: BM=128, BN=128, BK=32; 256 threads = 4 waves, each wave 64x64.
// ---------------------------------------------------------------------------
__global__ __launch_bounds__(256) void gemm1_kernel(
    const _Float16* __restrict__ Xh, const _Float16* __restrict__ Wh,
    const float* __restrict__ cosb, const float* __restrict__ sinb,
    _Float16* __restrict__ qout, _Float16* __restrict__ kout)
{
    __shared__ __align__(16) _Float16 lsA[128 * 32];
    __shared__ __align__(16) _Float16 lsB[128 * 32];
    const int tid  = threadIdx.x;
    const int lane = tid & 63;
    const int wv   = tid >> 6;       // 0..3
    const int wm   = wv & 1, wn = wv >> 1;
    const int m    = lane & 15, quad = lane >> 4;
    const int s0   = blockIdx.x * 128;   // M tile base (seq)
    const int n0   = blockIdx.y * 128;   // N tile base (out col)

    floatx4 acc[4][4];
    #pragma unroll
    for (int i = 0; i < 4; i++)
        #pragma unroll
        for (int j = 0; j < 4; j++)
            acc[i][j] = floatx4{0.f, 0.f, 0.f, 0.f};

    for (int k0 = 0; k0 < DIM; k0 += 32) {
        __syncthreads();
        #pragma unroll
        for (int t = 0; t < 2; t++) {
            int c  = tid + t * 256;       // 0..511 chunk id (16B chunks)
            int r  = c >> 2;              // row 0..127
            int cc = c & 3;               // 16B chunk within 64B row
            *(uint4*)(lsA + r * 32 + cc * 8) =
                *(const uint4*)(Xh + (long)(s0 + r) * DIM + k0 + cc * 8);
            *(uint4*)(lsB + r * 32 + cc * 8) =
                *(const uint4*)(Wh + (long)(n0 + r) * DIM + k0 + cc * 8);
        }
        __syncthreads();

        half8 aF[4], bF[4];
        #pragma unroll
        for (int i = 0; i < 4; i++)
            aF[i] = *(const half8*)(lsA + (wm * 64 + i * 16 + m) * 32 + quad * 8);
        #pragma unroll
        for (int j = 0; j < 4; j++)
            bF[j] = *(const half8*)(lsB + (wn * 64 + j * 16 + m) * 32 + quad * 8);
        #pragma unroll
        for (int i = 0; i < 4; i++)
            #pragma unroll
            for (int j = 0; j < 4; j++)
                acc[i][j] = __builtin_amdgcn_mfma_f32_16x16x32_f16(
                    aF[i], bF[j], acc[i][j], 0, 0, 0);
    }

    // Epilogue: RoPE + fp16 store. Wave covers 64 cols = exactly one head.
    // d = j*16 + m; partner (d +/- 32) is acc[i][j^2] same lane/reg.
    #pragma unroll
    for (int i = 0; i < 4; i++) {
        #pragma unroll
        for (int reg = 0; reg < 4; reg++) {
            int s = s0 + wm * 64 + i * 16 + quad * 4 + reg;
            #pragma unroll
            for (int j = 0; j < 4; j++) {
                int col = n0 + wn * 64 + j * 16 + m;
                int d   = j * 16 + m;        // col & 63
                float v = acc[i][j][reg];
                float partner = (j < 2) ? -acc[i][j + 2][reg] : acc[i][j - 2][reg];
                float cs = cosb[s * HD + d];
                float sn = sinb[s * HD + d];
                _Float16 o = (_Float16)(v * cs + partner * sn);
                if (col < NQ) {
                    int hq = col >> 6;
                    qout[((long)hq * SEQ + s) * HD + d] = o;
                } else {
                    int hk = (col - NQ) >> 6;
                    kout[((long)hk * SEQ + s) * HD + d] = o;
                }
            }
        }
    }
}

// ---------------------------------------------------------------------------
// Kernel 2: scores + softmax. Block = (head, 16 q-rows), 512 threads (8 waves).
// Each wave owns 256 cols: 16 mfma tiles kept entirely in registers.
// ---------------------------------------------------------------------------
__global__ __launch_bounds__(512) void attn_kernel(
    const _Float16* __restrict__ qf, const _Float16* __restrict__ kf,
    float* __restrict__ out)
{
    __shared__ float redm[8][16];
    __shared__ float redl[8][16];
    const int tid  = threadIdx.x;
    const int lane = tid & 63;
    const int w    = tid >> 6;      // wave 0..7
    const int m    = lane & 15, quad = lane >> 4;
    const int qb   = blockIdx.x;    // 0..127
    const int h    = blockIdx.y;    // 0..31
    const int kvh  = h >> 2;        // EXPAND = 4
    const int s0   = qb * 16;

    const _Float16* qbase = qf + ((long)h * SEQ + s0) * HD;
    const _Float16* kbase = kf + (long)kvh * SEQ * HD;

    half8 aF0 = *(const half8*)(qbase + (long)m * HD + quad * 8);
    half8 aF1 = *(const half8*)(qbase + (long)m * HD + 32 + quad * 8);

    floatx4 acc[16];
    #pragma unroll
    for (int ct = 0; ct < 16; ct++) {
        int n0 = w * 256 + ct * 16;
        const _Float16* kp = kbase + (long)(n0 + m) * HD + quad * 8;
        half8 bF0 = *(const half8*)(kp);
        half8 bF1 = *(const half8*)(kp + 32);
        floatx4 a = floatx4{0.f, 0.f, 0.f, 0.f};
        a = __builtin_amdgcn_mfma_f32_16x16x32_f16(aF0, bF0, a, 0, 0, 0);
        a = __builtin_amdgcn_mfma_f32_16x16x32_f16(aF1, bF1, a, 0, 0, 0);
        acc[ct] = a;
    }

    // Row max: row = quad*4 + reg, cols of this wave reduced via shfl over 16 lanes
    float gm[4], inv[4];
    #pragma unroll
    for (int r = 0; r < 4; r++) {
        float lm = acc[0][r];
        #pragma unroll
        for (int ct = 1; ct < 16; ct++) lm = fmaxf(lm, acc[ct][r]);
        for (int off = 1; off < 16; off <<= 1)
            lm = fmaxf(lm, __shfl_xor(lm, off));
        if (m == 0) redm[w][quad * 4 + r] = lm;
    }
    __syncthreads();
    #pragma unroll
    for (int r = 0; r < 4; r++) {
        int row = quad * 4 + r;
        float g = redm[0][row];
        #pragma unroll
        for (int ww = 1; ww < 8; ww++) g = fmaxf(g, redm[ww][row]);
        gm[r] = g;
    }
    // exp + row sum (exp stored back into acc)
    #pragma unroll
    for (int r = 0; r < 4; r++) {
        float ls = 0.f;
        #pragma unroll
        for (int ct = 0; ct < 16; ct++) {
            float e = __expf(acc[ct][r] - gm[r]);
            acc[ct][r] = e;
            ls += e;
        }
        for (int off = 1; off < 16; off <<= 1)
            ls += __shfl_xor(ls, off);
        if (m == 0) redl[w][quad * 4 + r] = ls;
    }
    __syncthreads();
    #pragma unroll
    for (int r = 0; r < 4; r++) {
        int row = quad * 4 + r;
        float t = 0.f;
        #pragma unroll
        for (int ww = 0; ww < 8; ww++) t += redl[ww][row];
        inv[r] = 1.0f / t;
    }
    // normalized write
    float* obase = out + ((long)h * SEQ + s0) * SEQ;
    #pragma unroll
    for (int ct = 0; ct < 16; ct++) {
        int n0 = w * 256 + ct * 16;
        #pragma unroll
        for (int r = 0; r < 4; r++) {
            int row = quad * 4 + r;
            obase[(long)row * SEQ + n0 + m] = acc[ct][r] * inv[r];
        }
    }
}

// ---------------------------------------------------------------------------
extern "C" void kernel_launch(void* const* d_in, const int* in_sizes, int n_in,
                              void* d_out, int out_size, void* d_ws, size_t ws_size,
                              hipStream_t stream) {
    const float* hidden = (const float*)d_in[0];
    const float* cosb   = (const float*)d_in[1];
    const float* sinb   = (const float*)d_in[2];
    // d_in[3] = attn_mask (all zeros, unused by reference) — ignored
    const float* Wq     = (const float*)d_in[4];
    const float* Wk     = (const float*)d_in[5];
    float* out = (float*)d_out;

    char* ws = (char*)d_ws;
    _Float16* Xh = (_Float16*)ws;                                   // 8 MiB
    _Float16* Wh = (_Float16*)(ws + 8388608);                       // 10 MiB
    _Float16* qf = (_Float16*)(ws + 8388608 + 10485760);            // 8 MiB
    _Float16* kf = (_Float16*)(ws + 8388608 + 10485760 + 8388608);  // 2 MiB

    convert_kernel<<<36864, 256, 0, stream>>>(hidden, Wq, Wk, Xh, Wh);
    gemm1_kernel<<<dim3(16, 20), 256, 0, stream>>>(Xh, Wh, cosb, sinb, qf, kf);
    attn_kernel<<<dim3(128, 32), 512, 0, stream>>>(qf, kf, out);
}

// Round 2
// 686.001 us; speedup vs baseline: 1.0251x; 1.0251x over previous
//
#include <hip/hip_runtime.h>
#include <hip/hip_bf16.h>

typedef _Float16 half8 __attribute__((ext_vector_type(8)));
typedef float floatx4 __attribute__((ext_vector_type(4)));

#define SEQ 2048
#define DIM 2048
#define HQ 32
#define HKV 8
#define HD 64
#define NQ (HQ*HD)    /* 2048 */
#define NK (HKV*HD)   /* 512  */
#define NTOT (NQ+NK)  /* 2560 */

#define GLOAD_LDS16(g, l) \
    __builtin_amdgcn_global_load_lds( \
        (const __attribute__((address_space(1))) void*)(g), \
        (__attribute__((address_space(3))) void*)(l), 16, 0, 0)

// ---------------------------------------------------------------------------
// Kernel 0: fp32 -> fp16 conversion, vectorized: float4 x2 -> half8 per thread
// ---------------------------------------------------------------------------
__global__ __launch_bounds__(256) void convert_kernel(
    const float* __restrict__ X, const float* __restrict__ Wq,
    const float* __restrict__ Wk, _Float16* __restrict__ Xh,
    _Float16* __restrict__ Wh)
{
    const long c   = (long)blockIdx.x * 256 + threadIdx.x;  // 8-float chunk id
    const long nxc = (long)SEQ * DIM / 8;                   // 524288
    const float* src;
    _Float16* dst;
    if (c < nxc) {
        src = X + c * 8;
        dst = Xh + c * 8;
    } else {
        long f = (c - nxc) * 8;
        src = (f < (long)NQ * DIM) ? Wq + f : Wk + (f - (long)NQ * DIM);
        dst = Wh + f;
    }
    float4 a = ((const float4*)src)[0];
    float4 b = ((const float4*)src)[1];
    half8 h = {(_Float16)a.x, (_Float16)a.y, (_Float16)a.z, (_Float16)a.w,
               (_Float16)b.x, (_Float16)b.y, (_Float16)b.z, (_Float16)b.w};
    *(half8*)dst = h;
}

// ---------------------------------------------------------------------------
// Kernel 1: QK projection GEMM + RoPE. BM=64, BN=128, BK=64.
// 256 threads = 4 waves (2x2), wave tile 32x64. global_load_lds staging with
// XOR chunk swizzle (applied on the global address; LDS DMA side is linear).
// ---------------------------------------------------------------------------
__global__ __launch_bounds__(256) void gemm1_kernel(
    const _Float16* __restrict__ Xh, const _Float16* __restrict__ Wh,
    const float* __restrict__ cosb, const float* __restrict__ sinb,
    _Float16* __restrict__ qout, _Float16* __restrict__ kout)
{
    __shared__ __align__(16) _Float16 lsA[64 * 64];    // 8 KB
    __shared__ __align__(16) _Float16 lsB[128 * 64];   // 16 KB
    const int tid  = threadIdx.x;
    const int lane = tid & 63;
    const int wv   = tid >> 6;
    const int wm   = wv & 1, wn = wv >> 1;
    const int m    = lane & 15, quad = lane >> 4;
    const int s0   = blockIdx.x * 64;
    const int n0   = blockIdx.y * 128;

    floatx4 acc[2][4];
    #pragma unroll
    for (int i = 0; i < 2; i++)
        #pragma unroll
        for (int j = 0; j < 4; j++)
            acc[i][j] = floatx4{0.f, 0.f, 0.f, 0.f};

    for (int k0 = 0; k0 < DIM; k0 += 64) {
        __syncthreads();
        // A: 64 rows x 8 chunks(16B) = 512 chunks, 2 rounds
        #pragma unroll
        for (int r = 0; r < 2; r++) {
            int c    = r * 256 + tid;
            int row  = c >> 3;
            int chg  = (c & 7) ^ (row & 7);   // swizzled global chunk
            GLOAD_LDS16(Xh + (long)(s0 + row) * DIM + k0 + chg * 8,
                        (char*)lsA + (r * 256 + wv * 64) * 16);
        }
        // B: 128 rows x 8 chunks = 1024 chunks, 4 rounds
        #pragma unroll
        for (int r = 0; r < 4; r++) {
            int c    = r * 256 + tid;
            int row  = c >> 3;
            int chg  = (c & 7) ^ (row & 7);
            GLOAD_LDS16(Wh + (long)(n0 + row) * DIM + k0 + chg * 8,
                        (char*)lsB + (r * 256 + wv * 64) * 16);
        }
        __syncthreads();   // drains vmcnt + lgkmcnt

        #pragma unroll
        for (int kk = 0; kk < 2; kk++) {
            half8 aF[2], bF[4];
            #pragma unroll
            for (int i = 0; i < 2; i++) {
                int row = wm * 32 + i * 16 + m;
                int pc  = ((kk << 2) | quad) ^ (m & 7);
                aF[i] = *(const half8*)(lsA + row * 64 + pc * 8);
            }
            #pragma unroll
            for (int j = 0; j < 4; j++) {
                int row = wn * 64 + j * 16 + m;
                int pc  = ((kk << 2) | quad) ^ (m & 7);
                bF[j] = *(const half8*)(lsB + row * 64 + pc * 8);
            }
            #pragma unroll
            for (int i = 0; i < 2; i++)
                #pragma unroll
                for (int j = 0; j < 4; j++)
                    acc[i][j] = __builtin_amdgcn_mfma_f32_16x16x32_f16(
                        aF[i], bF[j], acc[i][j], 0, 0, 0);
        }
    }

    // Epilogue: RoPE + fp16 store. Wave covers 64 cols = one head exactly.
    #pragma unroll
    for (int i = 0; i < 2; i++) {
        #pragma unroll
        for (int reg = 0; reg < 4; reg++) {
            int s = s0 + wm * 32 + i * 16 + quad * 4 + reg;
            #pragma unroll
            for (int j = 0; j < 4; j++) {
                int col = n0 + wn * 64 + j * 16 + m;
                int d   = j * 16 + m;
                float v = acc[i][j][reg];
                float partner = (j < 2) ? -acc[i][j + 2][reg] : acc[i][j - 2][reg];
                float cs = cosb[s * HD + d];
                float sn = sinb[s * HD + d];
                _Float16 o = (_Float16)(v * cs + partner * sn);
                if (col < NQ) {
                    int hq = col >> 6;
                    qout[((long)hq * SEQ + s) * HD + d] = o;
                } else {
                    int hk = (col - NQ) >> 6;
                    kout[((long)hk * SEQ + s) * HD + d] = o;
                }
            }
        }
    }
}

// ---------------------------------------------------------------------------
// Kernel 2: scores + softmax. Block = (16 q-rows, head), 512 threads (8 waves).
// Operand-swapped MFMA: A = K-tile (M = key), B = Q-tile (N = query).
// C layout: col(lane&15) = query, row(quad*4+reg) = key -> each lane holds
// 4 CONSECUTIVE keys of ONE query row => float4 stores, scalar softmax state.
// ---------------------------------------------------------------------------
__global__ __launch_bounds__(512) void attn_kernel(
    const _Float16* __restrict__ qf, const _Float16* __restrict__ kf,
    float* __restrict__ out)
{
    __shared__ float redm[8][16];
    __shared__ float redl[8][16];
    const int tid  = threadIdx.x;
    const int lane = tid & 63;
    const int w    = tid >> 6;      // wave 0..7, owns keys [w*256, w*256+256)
    const int m    = lane & 15, quad = lane >> 4;
    const int qb   = blockIdx.x;    // 0..127
    const int h    = blockIdx.y;    // 0..31
    const int kvh  = h >> 2;
    const int s0   = qb * 16;

    const _Float16* qbase = qf + ((long)h * SEQ + s0) * HD;
    const _Float16* kbase = kf + (long)kvh * SEQ * HD;

    // B operand = Q: B[n=lane&15][k=quad*8+j]
    half8 bQ0 = *(const half8*)(qbase + (long)m * HD + quad * 8);
    half8 bQ1 = *(const half8*)(qbase + (long)m * HD + 32 + quad * 8);

    floatx4 acc[16];
    #pragma unroll
    for (int ct = 0; ct < 16; ct++) {
        int n0 = w * 256 + ct * 16;
        const _Float16* kp = kbase + (long)(n0 + m) * HD + quad * 8;
        half8 aK0 = *(const half8*)(kp);
        half8 aK1 = *(const half8*)(kp + 32);
        floatx4 a = floatx4{0.f, 0.f, 0.f, 0.f};
        a = __builtin_amdgcn_mfma_f32_16x16x32_f16(aK0, bQ0, a, 0, 0, 0);
        a = __builtin_amdgcn_mfma_f32_16x16x32_f16(aK1, bQ1, a, 0, 0, 0);
        acc[ct] = a;
    }

    // Each lane: one q-row (q = s0+m), 64 key-values (16 ct x 4 reg).
    float lm = acc[0][0];
    #pragma unroll
    for (int ct = 0; ct < 16; ct++)
        #pragma unroll
        for (int r = 0; r < 4; r++) lm = fmaxf(lm, acc[ct][r]);
    lm = fmaxf(lm, __shfl_xor(lm, 16));
    lm = fmaxf(lm, __shfl_xor(lm, 32));
    if (quad == 0) redm[w][m] = lm;
    __syncthreads();
    float g = redm[0][m];
    #pragma unroll
    for (int ww = 1; ww < 8; ww++) g = fmaxf(g, redm[ww][m]);

    float ls = 0.f;
    #pragma unroll
    for (int ct = 0; ct < 16; ct++) {
        #pragma unroll
        for (int r = 0; r < 4; r++) {
            float e = __expf(acc[ct][r] - g);
            acc[ct][r] = e;
            ls += e;
        }
    }
    ls += __shfl_xor(ls, 16);
    ls += __shfl_xor(ls, 32);
    if (quad == 0) redl[w][m] = ls;
    __syncthreads();
    float tot = 0.f;
    #pragma unroll
    for (int ww = 0; ww < 8; ww++) tot += redl[ww][m];
    float inv = 1.0f / tot;

    // float4 stores: lane writes keys [n0+quad*4, +4) of row q=s0+m
    float* obase = out + ((long)h * SEQ + s0 + m) * SEQ + w * 256 + quad * 4;
    #pragma unroll
    for (int ct = 0; ct < 16; ct++) {
        floatx4 v = acc[ct];
        v[0] *= inv; v[1] *= inv; v[2] *= inv; v[3] *= inv;
        *(floatx4*)(obase + ct * 16) = v;
    }
}

// ---------------------------------------------------------------------------
extern "C" void kernel_launch(void* const* d_in, const int* in_sizes, int n_in,
                              void* d_out, int out_size, void* d_ws, size_t ws_size,
                              hipStream_t stream) {
    const float* hidden = (const float*)d_in[0];
    const float* cosb   = (const float*)d_in[1];
    const float* sinb   = (const float*)d_in[2];
    // d_in[3] = attn_mask (all zeros, unused by reference) — ignored
    const float* Wq     = (const float*)d_in[4];
    const float* Wk     = (const float*)d_in[5];
    float* out = (float*)d_out;

    char* ws = (char*)d_ws;
    _Float16* Xh = (_Float16*)ws;                                   // 8 MiB
    _Float16* Wh = (_Float16*)(ws + 8388608);                       // 10 MiB
    _Float16* qf = (_Float16*)(ws + 8388608 + 10485760);            // 8 MiB
    _Float16* kf = (_Float16*)(ws + 8388608 + 10485760 + 8388608);  // 2 MiB

    convert_kernel<<<4608, 256, 0, stream>>>(hidden, Wq, Wk, Xh, Wh);
    gemm1_kernel<<<dim3(32, 20), 256, 0, stream>>>(Xh, Wh, cosb, sinb, qf, kf);
    attn_kernel<<<dim3(128, 32), 512, 0, stream>>>(qf, kf, out);
}